// Round 1
// baseline (177.053 us; speedup 1.0000x reference)
//
#include <hip/hip_runtime.h>

using bf16 = __bf16;
typedef __bf16 bf16x8 __attribute__((ext_vector_type(8)));
typedef float f32x4 __attribute__((ext_vector_type(4)));

#define MFMA16(a, b, c) __builtin_amdgcn_mfma_f32_16x16x32_bf16((a), (b), (c), 0, 0, 0)

constexpr int S = 2048, DM = 512, H = 8, DK = 64, HD = 512;
constexpr int NBLK = 16, BLK = 128;
constexpr int Mrows = 8 * S;  // 16384
constexpr float LOG2E = 1.44269504088896340736f;

// ---------------- fp32 -> bf16 convert (hidden) ----------------
__global__ void k_conv(const float* __restrict__ x, bf16* __restrict__ y) {
  size_t i = ((size_t)blockIdx.x * 256 + threadIdx.x) * 8;
  float4 a = *(const float4*)(x + i);
  float4 b = *(const float4*)(x + i + 4);
  bf16x8 o;
  o[0] = (bf16)a.x; o[1] = (bf16)a.y; o[2] = (bf16)a.z; o[3] = (bf16)a.w;
  o[4] = (bf16)b.x; o[5] = (bf16)b.y; o[6] = (bf16)b.z; o[7] = (bf16)b.w;
  *(bf16x8*)(y + i) = o;
}

// ---------------- weight transpose + convert: Wt[n][k] = W[k][n] ----------------
__global__ void k_transw(const float* __restrict__ W, bf16* __restrict__ Wt) {
  __shared__ float tile[32][33];
  int k0 = blockIdx.x * 32, n0 = blockIdx.y * 32;
  int tx = threadIdx.x, ty = threadIdx.y;  // (32,8)
#pragma unroll
  for (int i = 0; i < 4; i++)
    tile[ty * 4 + i][tx] = W[(size_t)(k0 + ty * 4 + i) * 512 + n0 + tx];
  __syncthreads();
#pragma unroll
  for (int i = 0; i < 4; i++)
    Wt[(size_t)(n0 + ty * 4 + i) * 512 + k0 + tx] = (bf16)tile[tx][ty * 4 + i];
}

// ---------------- RoPE cos/sin table: ctab[s*32+i] = {cos, sin}(s * 10000^(-i/32)) ----------------
__global__ void k_ctab(float2* __restrict__ ctab) {
  int idx = blockIdx.x * 256 + threadIdx.x;  // 65536 entries
  int s = idx >> 5, i = idx & 31;
  float invf = exp2f(-(float)i * (13.287712379549449f / 32.0f));  // 10000^(-i/32)
  float ang = (float)s * invf;
  ctab[idx] = make_float2(cosf(ang), sinf(ang));
}

// ---------------- 128x128x(K=512) bf16 GEMM, QKV variant with fused RoPE ----------------
// A: [16384,512] bf16 row-major.  Wt: [512,512] bf16, [N][K].  out bf16 [16384,512].
__global__ __launch_bounds__(256) void k_gemm_qkv(
    const bf16* __restrict__ Xb,
    const bf16* __restrict__ Wtq, const bf16* __restrict__ Wtk, const bf16* __restrict__ Wtv,
    bf16* __restrict__ Qo, bf16* __restrict__ Ko, bf16* __restrict__ Vo,
    const float2* __restrict__ ctab) {
  const int z = blockIdx.z;
  const bf16* Wt = (z == 0) ? Wtq : ((z == 1) ? Wtk : Wtv);
  bf16* dst = (z == 0) ? Qo : ((z == 1) ? Ko : Vo);
  const bool rope = (z < 2);

  __shared__ __align__(16) char Asm[128 * 64];  // 128 rows x 32 bf16, 16B-chunk XOR swizzle
  __shared__ __align__(16) char Bsm[128 * 64];

  const int t = threadIdx.x, l = t & 63, wid = t >> 6;
  const int l15 = l & 15, l4 = l >> 4;
  const int wm = wid >> 1, wn = wid & 1;
  const size_t arow0 = (size_t)blockIdx.x * 128;
  const size_t brow0 = (size_t)blockIdx.y * 128;

  f32x4 acc[4][4] = {};
  const int srow = t >> 2, schunk = t & 3;

  for (int kt = 0; kt < 16; ++kt) {
    const int k0 = kt * 32;
    bf16x8 ra0 = *(const bf16x8*)(Xb + (arow0 + srow) * 512 + k0 + schunk * 8);
    bf16x8 ra1 = *(const bf16x8*)(Xb + (arow0 + 64 + srow) * 512 + k0 + schunk * 8);
    bf16x8 rb0 = *(const bf16x8*)(Wt + (brow0 + srow) * 512 + k0 + schunk * 8);
    bf16x8 rb1 = *(const bf16x8*)(Wt + (brow0 + 64 + srow) * 512 + k0 + schunk * 8);
    __syncthreads();
    {
      int r0 = srow, c0 = schunk ^ (r0 & 3);
      *(bf16x8*)(Asm + r0 * 64 + c0 * 16) = ra0;
      *(bf16x8*)(Bsm + r0 * 64 + c0 * 16) = rb0;
      int r1 = srow + 64, c1 = schunk ^ (r1 & 3);
      *(bf16x8*)(Asm + r1 * 64 + c1 * 16) = ra1;
      *(bf16x8*)(Bsm + r1 * 64 + c1 * 16) = rb1;
    }
    __syncthreads();
    bf16x8 af[4], bfr[4];
#pragma unroll
    for (int mi = 0; mi < 4; mi++) {
      int row = wm * 64 + mi * 16 + l15;
      af[mi] = *(const bf16x8*)(Asm + row * 64 + ((l4 ^ (row & 3)) * 16));
    }
#pragma unroll
    for (int ni = 0; ni < 4; ni++) {
      int row = wn * 64 + ni * 16 + l15;
      bfr[ni] = *(const bf16x8*)(Bsm + row * 64 + ((l4 ^ (row & 3)) * 16));
    }
#pragma unroll
    for (int mi = 0; mi < 4; mi++)
#pragma unroll
      for (int ni = 0; ni < 4; ni++)
        acc[mi][ni] = MFMA16(af[mi], bfr[ni], acc[mi][ni]);
  }

#pragma unroll
  for (int mi = 0; mi < 4; mi++) {
#pragma unroll
    for (int r = 0; r < 4; r++) {
      int grow = (int)arow0 + wm * 64 + mi * 16 + l4 * 4 + r;
      size_t rowoff = (size_t)grow * 512 + brow0 + wn * 64;
      if (rope) {
        int s = grow & (S - 1);
        float2 cs0 = ctab[s * 32 + l15];
        float2 cs1 = ctab[s * 32 + 16 + l15];
#pragma unroll
        for (int ni = 0; ni < 4; ni++) {
          float a = acc[mi][ni][r];
          float b = acc[mi][ni ^ 2][r];
          float2 cs = (ni & 1) ? cs1 : cs0;
          float val = (ni < 2) ? (a * cs.x - b * cs.y) : (a * cs.x + b * cs.y);
          dst[rowoff + ni * 16 + l15] = (bf16)val;
        }
      } else {
#pragma unroll
        for (int ni = 0; ni < 4; ni++)
          dst[rowoff + ni * 16 + l15] = (bf16)acc[mi][ni][r];
      }
    }
  }
}

// ---------------- output projection GEMM: AO[16384,512]bf16 x Wot -> fp32 ----------------
__global__ __launch_bounds__(256) void k_gemm_out(
    const bf16* __restrict__ A, const bf16* __restrict__ Wt, float* __restrict__ out) {
  __shared__ __align__(16) char Asm[128 * 64];
  __shared__ __align__(16) char Bsm[128 * 64];

  const int t = threadIdx.x, l = t & 63, wid = t >> 6;
  const int l15 = l & 15, l4 = l >> 4;
  const int wm = wid >> 1, wn = wid & 1;
  const size_t arow0 = (size_t)blockIdx.x * 128;
  const size_t brow0 = (size_t)blockIdx.y * 128;

  f32x4 acc[4][4] = {};
  const int srow = t >> 2, schunk = t & 3;

  for (int kt = 0; kt < 16; ++kt) {
    const int k0 = kt * 32;
    bf16x8 ra0 = *(const bf16x8*)(A + (arow0 + srow) * 512 + k0 + schunk * 8);
    bf16x8 ra1 = *(const bf16x8*)(A + (arow0 + 64 + srow) * 512 + k0 + schunk * 8);
    bf16x8 rb0 = *(const bf16x8*)(Wt + (brow0 + srow) * 512 + k0 + schunk * 8);
    bf16x8 rb1 = *(const bf16x8*)(Wt + (brow0 + 64 + srow) * 512 + k0 + schunk * 8);
    __syncthreads();
    {
      int r0 = srow, c0 = schunk ^ (r0 & 3);
      *(bf16x8*)(Asm + r0 * 64 + c0 * 16) = ra0;
      *(bf16x8*)(Bsm + r0 * 64 + c0 * 16) = rb0;
      int r1 = srow + 64, c1 = schunk ^ (r1 & 3);
      *(bf16x8*)(Asm + r1 * 64 + c1 * 16) = ra1;
      *(bf16x8*)(Bsm + r1 * 64 + c1 * 16) = rb1;
    }
    __syncthreads();
    bf16x8 af[4], bfr[4];
#pragma unroll
    for (int mi = 0; mi < 4; mi++) {
      int row = wm * 64 + mi * 16 + l15;
      af[mi] = *(const bf16x8*)(Asm + row * 64 + ((l4 ^ (row & 3)) * 16));
    }
#pragma unroll
    for (int ni = 0; ni < 4; ni++) {
      int row = wn * 64 + ni * 16 + l15;
      bfr[ni] = *(const bf16x8*)(Bsm + row * 64 + ((l4 ^ (row & 3)) * 16));
    }
#pragma unroll
    for (int mi = 0; mi < 4; mi++)
#pragma unroll
      for (int ni = 0; ni < 4; ni++)
        acc[mi][ni] = MFMA16(af[mi], bfr[ni], acc[mi][ni]);
  }

#pragma unroll
  for (int mi = 0; mi < 4; mi++)
#pragma unroll
    for (int r = 0; r < 4; r++) {
      int grow = (int)arow0 + wm * 64 + mi * 16 + l4 * 4 + r;
      size_t rowoff = (size_t)grow * 512 + brow0 + wn * 64;
#pragma unroll
      for (int ni = 0; ni < 4; ni++)
        out[rowoff + ni * 16 + l15] = acc[mi][ni][r];
    }
}

// ---------------- block-banded flash attention ----------------
// grid (NB=16, H=8, B=8), 256 thr = 4 waves x 32 query rows. Window = blocks {nb-1, nb, nb+1}.
__global__ __launch_bounds__(256) void k_attn(
    const bf16* __restrict__ Q, const bf16* __restrict__ K, const bf16* __restrict__ V,
    bf16* __restrict__ O) {
  const int nb = blockIdx.x, h = blockIdx.y, bb = blockIdx.z;
  const int t = threadIdx.x, l = t & 63, wid = t >> 6;
  const int l15 = l & 15, l4 = l >> 4;

  __shared__ __align__(16) char Ksm[128 * 128];      // [128 keys][64 bf16], XOR swizzled
  __shared__ __align__(16) char Vsm[64 * 136 * 2];   // Vt[d][key], stride 136 (16B aligned)
  __shared__ __align__(16) char Psm[4][32 * 128];    // per-wave P half [32][64] bf16, swizzled

  const size_t qrow0 = (size_t)bb * S + (size_t)nb * BLK;
  const int colh = h * DK;

  bf16x8 aq[2][2];
#pragma unroll
  for (int mi = 0; mi < 2; mi++)
#pragma unroll
    for (int kc = 0; kc < 2; kc++)
      aq[mi][kc] = *(const bf16x8*)(Q + (qrow0 + wid * 32 + mi * 16 + l15) * HD + colh + kc * 32 + l4 * 8);

  f32x4 oacc[2][4] = {};
  float mrun[2][4], lrun[2][4];
#pragma unroll
  for (int mi = 0; mi < 2; mi++)
#pragma unroll
    for (int r = 0; r < 4; r++) { mrun[mi][r] = -3e38f; lrun[mi][r] = 0.f; }

  bool first = true;
  for (int c = 0; c < 3; ++c) {
    int kb = nb - 1 + c;
    if (kb < 0 || kb >= NBLK) continue;
    const size_t krow0 = (size_t)bb * S + (size_t)kb * BLK;

    if (!first) __syncthreads();
    first = false;

    {  // stage K, swizzled
      int chunk = t & 7;
#pragma unroll
      for (int p = 0; p < 4; p++) {
        int key = p * 32 + (t >> 3);
        bf16x8 v = *(const bf16x8*)(K + (krow0 + key) * HD + colh + chunk * 8);
        *(bf16x8*)(Ksm + key * 128 + ((chunk ^ (key & 7)) * 16)) = v;
      }
    }
    {  // stage V transposed
      int key = t & 127, d0 = (t >> 7) * 32;
#pragma unroll
      for (int q = 0; q < 4; q++) {
        bf16x8 v = *(const bf16x8*)(V + (krow0 + key) * HD + colh + d0 + q * 8);
#pragma unroll
        for (int j = 0; j < 8; j++)
          *(bf16*)(Vsm + ((d0 + q * 8 + j) * 136 + key) * 2) = v[j];
      }
    }
    __syncthreads();

    // scores: [32 rows][128 keys] per wave
    f32x4 sc[2][8];
#pragma unroll
    for (int ni = 0; ni < 8; ni++) {
      int key = ni * 16 + l15;
      bf16x8 bk0 = *(const bf16x8*)(Ksm + key * 128 + ((l4 ^ (key & 7)) * 16));
      bf16x8 bk1 = *(const bf16x8*)(Ksm + key * 128 + (((4 + l4) ^ (key & 7)) * 16));
#pragma unroll
      for (int mi = 0; mi < 2; mi++) {
        f32x4 zz = {0.f, 0.f, 0.f, 0.f};
        zz = MFMA16(aq[mi][0], bk0, zz);
        sc[mi][ni] = MFMA16(aq[mi][1], bk1, zz);
      }
    }

    if (c == 0) {  // left block: valid iff kj >= qi
#pragma unroll
      for (int mi = 0; mi < 2; mi++)
#pragma unroll
        for (int ni = 0; ni < 8; ni++)
#pragma unroll
          for (int r = 0; r < 4; r++) {
            int kj = ni * 16 + l15, qi = wid * 32 + mi * 16 + l4 * 4 + r;
            if (kj < qi) sc[mi][ni][r] = -1e30f;
          }
    } else if (c == 2) {  // right block: valid iff kj <= qi
#pragma unroll
      for (int mi = 0; mi < 2; mi++)
#pragma unroll
        for (int ni = 0; ni < 8; ni++)
#pragma unroll
          for (int r = 0; r < 4; r++) {
            int kj = ni * 16 + l15, qi = wid * 32 + mi * 16 + l4 * 4 + r;
            if (kj > qi) sc[mi][ni][r] = -1e30f;
          }
    }

    // online softmax
#pragma unroll
    for (int mi = 0; mi < 2; mi++)
#pragma unroll
      for (int r = 0; r < 4; r++) {
        float m = sc[mi][0][r];
#pragma unroll
        for (int ni = 1; ni < 8; ni++) m = fmaxf(m, sc[mi][ni][r]);
        m = fmaxf(m, __shfl_xor(m, 1));
        m = fmaxf(m, __shfl_xor(m, 2));
        m = fmaxf(m, __shfl_xor(m, 4));
        m = fmaxf(m, __shfl_xor(m, 8));
        float mnew = fmaxf(mrun[mi][r], m);
        float alpha = exp2f((mrun[mi][r] - mnew) * LOG2E);
#pragma unroll
        for (int nv = 0; nv < 4; nv++) oacc[mi][nv][r] *= alpha;
        float rs = 0.f;
#pragma unroll
        for (int ni = 0; ni < 8; ni++) {
          float p = exp2f((sc[mi][ni][r] - mnew) * LOG2E);
          sc[mi][ni][r] = p;
          rs += p;
        }
        rs += __shfl_xor(rs, 1);
        rs += __shfl_xor(rs, 2);
        rs += __shfl_xor(rs, 4);
        rs += __shfl_xor(rs, 8);
        lrun[mi][r] = lrun[mi][r] * alpha + rs;
        mrun[mi][r] = mnew;
      }

    // PV in two halves of 64 keys (wave-private P buffer round-trip)
    char* Pw = &Psm[wid][0];
#pragma unroll
    for (int hf = 0; hf < 2; hf++) {
#pragma unroll
      for (int mi = 0; mi < 2; mi++)
#pragma unroll
        for (int nq = 0; nq < 4; nq++)
#pragma unroll
          for (int r = 0; r < 4; r++) {
            int ni = hf * 4 + nq;
            int row = mi * 16 + l4 * 4 + r;
            int colb = (nq * 16 + l15) * 2;
            *(bf16*)(Pw + row * 128 + (colb ^ ((row & 7) << 4))) = (bf16)sc[mi][ni][r];
          }
#pragma unroll
      for (int kc = 0; kc < 2; kc++) {
        bf16x8 pf[2];
#pragma unroll
        for (int mi = 0; mi < 2; mi++) {
          int row = mi * 16 + l15;
          pf[mi] = *(const bf16x8*)(Pw + row * 128 + (((kc * 4 + l4) * 16) ^ ((row & 7) << 4)));
        }
#pragma unroll
        for (int nv = 0; nv < 4; nv++) {
          int d = nv * 16 + l15;
          bf16x8 vf = *(const bf16x8*)(Vsm + ((size_t)d * 136 + hf * 64 + kc * 32 + l4 * 8) * 2);
#pragma unroll
          for (int mi = 0; mi < 2; mi++)
            oacc[mi][nv] = MFMA16(pf[mi], vf, oacc[mi][nv]);
        }
      }
    }
  }

#pragma unroll
  for (int mi = 0; mi < 2; mi++)
#pragma unroll
    for (int r = 0; r < 4; r++) {
      float inv = 1.0f / lrun[mi][r];
      int row = wid * 32 + mi * 16 + l4 * 4 + r;
      size_t go = (qrow0 + row) * HD + colh;
#pragma unroll
      for (int nv = 0; nv < 4; nv++)
        O[go + nv * 16 + l15] = (bf16)(oacc[mi][nv][r] * inv);
    }
}

extern "C" void kernel_launch(void* const* d_in, const int* in_sizes, int n_in,
                              void* d_out, int out_size, void* d_ws, size_t ws_size,
                              hipStream_t stream) {
  const float* hs = (const float*)d_in[0];
  const float* Wq = (const float*)d_in[1];
  const float* Wk = (const float*)d_in[2];
  const float* Wv = (const float*)d_in[3];
  const float* Wo = (const float*)d_in[4];
  float* out = (float*)d_out;

  char* ws = (char*)d_ws;
  const size_t MB = 1u << 20;
  bf16* Xb = (bf16*)(ws);                 // 16 MB, reused as attention output
  bf16* Qb = (bf16*)(ws + 16 * MB);
  bf16* Kb = (bf16*)(ws + 32 * MB);
  bf16* Vb = (bf16*)(ws + 48 * MB);
  bf16* Wtq = (bf16*)(ws + 64 * MB);
  bf16* Wtk = Wtq + 512 * 512;
  bf16* Wtv = Wtk + 512 * 512;
  bf16* Wto = Wtv + 512 * 512;
  float2* ctab = (float2*)(ws + 64 * MB + 4 * 512 * 512 * sizeof(bf16));
  bf16* AO = Xb;

  k_conv<<<dim3(Mrows * DM / (256 * 8)), dim3(256), 0, stream>>>(hs, Xb);
  k_transw<<<dim3(16, 16), dim3(32, 8), 0, stream>>>(Wq, Wtq);
  k_transw<<<dim3(16, 16), dim3(32, 8), 0, stream>>>(Wk, Wtk);
  k_transw<<<dim3(16, 16), dim3(32, 8), 0, stream>>>(Wv, Wtv);
  k_transw<<<dim3(16, 16), dim3(32, 8), 0, stream>>>(Wo, Wto);
  k_ctab<<<dim3(S * 32 / 256), dim3(256), 0, stream>>>(ctab);
  k_gemm_qkv<<<dim3(Mrows / 128, 4, 3), dim3(256), 0, stream>>>(Xb, Wtq, Wtk, Wtv, Qb, Kb, Vb, ctab);
  k_attn<<<dim3(NBLK, H, 8), dim3(256), 0, stream>>>(Qb, Kb, Vb, AO);
  k_gemm_out<<<dim3(Mrows / 128, 4), dim3(256), 0, stream>>>(AO, Wto, out);
}

// Round 2
// 151.719 us; speedup vs baseline: 1.1670x; 1.1670x over previous
//
#include <hip/hip_runtime.h>

using bf16 = __bf16;
typedef __bf16 bf16x8 __attribute__((ext_vector_type(8)));
typedef __bf16 bf16x4 __attribute__((ext_vector_type(4)));
typedef float f32x4 __attribute__((ext_vector_type(4)));

#define MFMA16(a, b, c) __builtin_amdgcn_mfma_f32_16x16x32_bf16((a), (b), (c), 0, 0, 0)

constexpr int S = 2048, DM = 512, H = 8, DK = 64, HD = 512;
constexpr int NBLK = 16, BLK = 128;
constexpr int Mrows = 8 * S;  // 16384
constexpr float LOG2E = 1.44269504088896340736f;

__device__ __forceinline__ void gll16(const void* g, void* l) {
  __builtin_amdgcn_global_load_lds((const __attribute__((address_space(1))) unsigned int*)g,
                                   (__attribute__((address_space(3))) unsigned int*)l, 16, 0, 0);
}

// ---------------- fp32 -> bf16 convert (hidden) ----------------
__global__ void k_conv(const float* __restrict__ x, bf16* __restrict__ y) {
  size_t i = ((size_t)blockIdx.x * 256 + threadIdx.x) * 8;
  float4 a = *(const float4*)(x + i);
  float4 b = *(const float4*)(x + i + 4);
  bf16x8 o;
  o[0] = (bf16)a.x; o[1] = (bf16)a.y; o[2] = (bf16)a.z; o[3] = (bf16)a.w;
  o[4] = (bf16)b.x; o[5] = (bf16)b.y; o[6] = (bf16)b.z; o[7] = (bf16)b.w;
  *(bf16x8*)(y + i) = o;
}

// ---------------- weight transpose + convert: Wt[n][k] = W[k][n] ----------------
__global__ void k_transw(const float* __restrict__ W, bf16* __restrict__ Wt) {
  __shared__ float tile[32][33];
  int k0 = blockIdx.x * 32, n0 = blockIdx.y * 32;
  int tx = threadIdx.x, ty = threadIdx.y;  // (32,8)
#pragma unroll
  for (int i = 0; i < 4; i++)
    tile[ty * 4 + i][tx] = W[(size_t)(k0 + ty * 4 + i) * 512 + n0 + tx];
  __syncthreads();
#pragma unroll
  for (int i = 0; i < 4; i++)
    Wt[(size_t)(n0 + ty * 4 + i) * 512 + k0 + tx] = (bf16)tile[tx][ty * 4 + i];
}

// ---------------- RoPE cos/sin table ----------------
__global__ void k_ctab(float2* __restrict__ ctab) {
  int idx = blockIdx.x * 256 + threadIdx.x;  // 65536 entries
  int s = idx >> 5, i = idx & 31;
  float invf = exp2f(-(float)i * (13.287712379549449f / 32.0f));  // 10000^(-i/32)
  float ang = (float)s * invf;
  ctab[idx] = make_float2(cosf(ang), sinf(ang));
}

// ---------------- 128x128x(K=512) bf16 GEMM, QKV variant with fused RoPE ----------------
// z=0: Q (rope) -> Qo flat.  z=1: K (rope) -> Ko flat.  z=2: V -> Vt[bh][d][s].
__global__ __launch_bounds__(256) void k_gemm_qkv(
    const bf16* __restrict__ Xb,
    const bf16* __restrict__ Wtq, const bf16* __restrict__ Wtk, const bf16* __restrict__ Wtv,
    bf16* __restrict__ Qo, bf16* __restrict__ Ko, bf16* __restrict__ Vt,
    const float2* __restrict__ ctab) {
  const int z = blockIdx.z;
  const bf16* Wt = (z == 0) ? Wtq : ((z == 1) ? Wtk : Wtv);
  bf16* dst = (z == 0) ? Qo : Ko;
  const bool rope = (z < 2);

  __shared__ __align__(16) char Asm[128 * 64];  // 128 rows x 32 bf16, 16B-chunk XOR swizzle
  __shared__ __align__(16) char Bsm[128 * 64];

  const int t = threadIdx.x, l = t & 63, wid = t >> 6;
  const int l15 = l & 15, l4 = l >> 4;
  const int wm = wid >> 1, wn = wid & 1;
  const size_t arow0 = (size_t)blockIdx.x * 128;
  const size_t brow0 = (size_t)blockIdx.y * 128;

  f32x4 acc[4][4] = {};
  const int rs = wid * 16 + (l >> 2);          // linear dest row (issue 0)
  const int cs = (l & 3) ^ ((l >> 2) & 3);     // pre-swizzled source chunk

  for (int kt = 0; kt < 16; ++kt) {
    const int k0 = kt * 32;
    __syncthreads();
    gll16(Xb + (arow0 + rs) * 512 + k0 + cs * 8,      Asm + wid * 1024);
    gll16(Xb + (arow0 + 64 + rs) * 512 + k0 + cs * 8, Asm + 4096 + wid * 1024);
    gll16(Wt + (brow0 + rs) * 512 + k0 + cs * 8,      Bsm + wid * 1024);
    gll16(Wt + (brow0 + 64 + rs) * 512 + k0 + cs * 8, Bsm + 4096 + wid * 1024);
    __syncthreads();
    bf16x8 af[4], bfr[4];
#pragma unroll
    for (int mi = 0; mi < 4; mi++) {
      int row = wm * 64 + mi * 16 + l15;
      af[mi] = *(const bf16x8*)(Asm + row * 64 + ((l4 ^ (row & 3)) * 16));
    }
#pragma unroll
    for (int ni = 0; ni < 4; ni++) {
      int row = wn * 64 + ni * 16 + l15;
      bfr[ni] = *(const bf16x8*)(Bsm + row * 64 + ((l4 ^ (row & 3)) * 16));
    }
#pragma unroll
    for (int mi = 0; mi < 4; mi++)
#pragma unroll
      for (int ni = 0; ni < 4; ni++)
        acc[mi][ni] = MFMA16(af[mi], bfr[ni], acc[mi][ni]);
  }

  if (z == 2) {
    // write V^T: Vt[(b*H + h)*64 + d][s], pack 4 consecutive s (r dim) per store
    const int b = (int)(arow0 >> 11);
#pragma unroll
    for (int mi = 0; mi < 4; mi++) {
      int scol = (int)(arow0 & 2047) + wm * 64 + mi * 16 + l4 * 4;
#pragma unroll
      for (int ni = 0; ni < 4; ni++) {
        int col = (int)brow0 + wn * 64 + ni * 16 + l15;
        int hh = col >> 6, dd = col & 63;
        bf16x4 pk = {(bf16)acc[mi][ni][0], (bf16)acc[mi][ni][1],
                     (bf16)acc[mi][ni][2], (bf16)acc[mi][ni][3]};
        *(bf16x4*)(Vt + ((size_t)((b * H + hh) * 64 + dd)) * 2048 + scol) = pk;
      }
    }
    return;
  }

#pragma unroll
  for (int mi = 0; mi < 4; mi++) {
#pragma unroll
    for (int r = 0; r < 4; r++) {
      int grow = (int)arow0 + wm * 64 + mi * 16 + l4 * 4 + r;
      size_t rowoff = (size_t)grow * 512 + brow0 + wn * 64;
      if (rope) {
        int s = grow & (S - 1);
        float2 cs0 = ctab[s * 32 + l15];
        float2 cs1 = ctab[s * 32 + 16 + l15];
#pragma unroll
        for (int ni = 0; ni < 4; ni++) {
          float a = acc[mi][ni][r];
          float b = acc[mi][ni ^ 2][r];
          float2 cc = (ni & 1) ? cs1 : cs0;
          float val = (ni < 2) ? (a * cc.x - b * cc.y) : (a * cc.x + b * cc.y);
          dst[rowoff + ni * 16 + l15] = (bf16)val;
        }
      } else {
#pragma unroll
        for (int ni = 0; ni < 4; ni++)
          dst[rowoff + ni * 16 + l15] = (bf16)acc[mi][ni][r];
      }
    }
  }
}

// ---------------- output projection GEMM -> fp32 ----------------
__global__ __launch_bounds__(256) void k_gemm_out(
    const bf16* __restrict__ A, const bf16* __restrict__ Wt, float* __restrict__ out) {
  __shared__ __align__(16) char Asm[128 * 64];
  __shared__ __align__(16) char Bsm[128 * 64];

  const int t = threadIdx.x, l = t & 63, wid = t >> 6;
  const int l15 = l & 15, l4 = l >> 4;
  const int wm = wid >> 1, wn = wid & 1;
  const size_t arow0 = (size_t)blockIdx.x * 128;
  const size_t brow0 = (size_t)blockIdx.y * 128;

  f32x4 acc[4][4] = {};
  const int rs = wid * 16 + (l >> 2);
  const int cs = (l & 3) ^ ((l >> 2) & 3);

  for (int kt = 0; kt < 16; ++kt) {
    const int k0 = kt * 32;
    __syncthreads();
    gll16(A + (arow0 + rs) * 512 + k0 + cs * 8,       Asm + wid * 1024);
    gll16(A + (arow0 + 64 + rs) * 512 + k0 + cs * 8,  Asm + 4096 + wid * 1024);
    gll16(Wt + (brow0 + rs) * 512 + k0 + cs * 8,      Bsm + wid * 1024);
    gll16(Wt + (brow0 + 64 + rs) * 512 + k0 + cs * 8, Bsm + 4096 + wid * 1024);
    __syncthreads();
    bf16x8 af[4], bfr[4];
#pragma unroll
    for (int mi = 0; mi < 4; mi++) {
      int row = wm * 64 + mi * 16 + l15;
      af[mi] = *(const bf16x8*)(Asm + row * 64 + ((l4 ^ (row & 3)) * 16));
    }
#pragma unroll
    for (int ni = 0; ni < 4; ni++) {
      int row = wn * 64 + ni * 16 + l15;
      bfr[ni] = *(const bf16x8*)(Bsm + row * 64 + ((l4 ^ (row & 3)) * 16));
    }
#pragma unroll
    for (int mi = 0; mi < 4; mi++)
#pragma unroll
      for (int ni = 0; ni < 4; ni++)
        acc[mi][ni] = MFMA16(af[mi], bfr[ni], acc[mi][ni]);
  }

#pragma unroll
  for (int mi = 0; mi < 4; mi++)
#pragma unroll
    for (int r = 0; r < 4; r++) {
      int grow = (int)arow0 + wm * 64 + mi * 16 + l4 * 4 + r;
      size_t rowoff = (size_t)grow * 512 + brow0 + wn * 64;
#pragma unroll
      for (int ni = 0; ni < 4; ni++)
        out[rowoff + ni * 16 + l15] = acc[mi][ni][r];
    }
}

// ---------------- block-banded flash attention (swapped-operand form) ----------------
// grid (16, 8, 8), 256 thr = 4 waves x 32 q-rows.  Lane owns q = l&15 column; keys in-lane.
__global__ __launch_bounds__(256) void k_attn(
    const bf16* __restrict__ Q, const bf16* __restrict__ K, const bf16* __restrict__ Vt,
    bf16* __restrict__ O) {
  const int nb = blockIdx.x, h = blockIdx.y, bb = blockIdx.z;
  const int t = threadIdx.x, l = t & 63, wid = t >> 6;
  const int l15 = l & 15, l4 = l >> 4;

  __shared__ __align__(16) char Ksm[128 * 128];   // [key][64 dk], 8x16B chunks, ^ (key&7)
  __shared__ __align__(16) char Vsm[64 * 256];    // [d][128 key], 16x16B chunks, ^ (d&15)
  __shared__ __align__(16) char Psm[4][16 * 80];  // per-wave P^T [q=16][32 keys] rows padded to 80B

  const int bh = bb * H + h;
  const size_t qrow0 = (size_t)bb * S + (size_t)nb * BLK;
  const int colh = h * DK;

  // Q B-frags: lane q = l15, dk = kc*32 + l4*8
  bf16x8 aq[2][2];
#pragma unroll
  for (int mi = 0; mi < 2; mi++)
#pragma unroll
    for (int kc = 0; kc < 2; kc++)
      aq[mi][kc] = *(const bf16x8*)(Q + (qrow0 + wid * 32 + mi * 16 + l15) * HD + colh + kc * 32 + l4 * 8);

  f32x4 oacc[2][4] = {};                 // O^T: d = dv*16 + l4*4 + r, q = l15 (per mi)
  float mrun[2] = {-3e38f, -3e38f}, lrun[2] = {0.f, 0.f};

  // staging maps (linear LDS dest + inverse-swizzled source)
  const int kRow = t >> 3, kC = (t & 7) ^ ((t >> 3) & 7);
  const int vD = t >> 4, vC = (t & 15) ^ (t >> 4);
  char* Pw = &Psm[wid][0];

  for (int c = 0; c < 3; ++c) {
    int kb = nb - 1 + c;
    if (kb < 0 || kb >= NBLK) continue;
    const size_t krow0 = (size_t)bb * S + (size_t)kb * BLK;
    const int ks0 = kb * BLK;

    __syncthreads();  // prior chunk's LDS reads done before overwrite
#pragma unroll
    for (int p = 0; p < 4; p++)
      gll16(K + (krow0 + p * 32 + kRow) * HD + colh + kC * 8, Ksm + p * 4096 + wid * 1024);
#pragma unroll
    for (int p = 0; p < 4; p++)
      gll16(Vt + ((size_t)(bh * 64 + p * 16 + vD)) * 2048 + ks0 + vC * 8, Vsm + p * 4096 + wid * 1024);
    __syncthreads();

    // S^T = K x Q^T : D[key][q]
    f32x4 st[2][8];
#pragma unroll
    for (int ni = 0; ni < 8; ni++) {
      int key = ni * 16 + l15;
      bf16x8 kf0 = *(const bf16x8*)(Ksm + key * 128 + ((l4 ^ (key & 7)) * 16));
      bf16x8 kf1 = *(const bf16x8*)(Ksm + key * 128 + (((4 + l4) ^ (key & 7)) * 16));
#pragma unroll
      for (int mi = 0; mi < 2; mi++) {
        f32x4 zz = {0.f, 0.f, 0.f, 0.f};
        zz = MFMA16(kf0, aq[mi][0], zz);
        st[mi][ni] = MFMA16(kf1, aq[mi][1], zz);
      }
    }

    // band mask (keys now in-lane: key = ni*16 + l4*4 + r, q = wid*32 + mi*16 + l15)
    if (c != 1) {
#pragma unroll
      for (int mi = 0; mi < 2; mi++) {
        int qi = wid * 32 + mi * 16 + l15;
#pragma unroll
        for (int ni = 0; ni < 8; ni++)
#pragma unroll
          for (int r = 0; r < 4; r++) {
            int kj = ni * 16 + l4 * 4 + r;
            bool bad = (c == 0) ? (kj < qi) : (kj > qi);
            if (bad) st[mi][ni][r] = -1e30f;
          }
      }
    }

    // online softmax: in-lane over 32 keys + 2 shfl across l4 groups
#pragma unroll
    for (int mi = 0; mi < 2; mi++) {
      f32x4 mm = st[mi][0];
#pragma unroll
      for (int ni = 1; ni < 8; ni++) {
        mm[0] = fmaxf(mm[0], st[mi][ni][0]); mm[1] = fmaxf(mm[1], st[mi][ni][1]);
        mm[2] = fmaxf(mm[2], st[mi][ni][2]); mm[3] = fmaxf(mm[3], st[mi][ni][3]);
      }
      float m = fmaxf(fmaxf(mm[0], mm[1]), fmaxf(mm[2], mm[3]));
      m = fmaxf(m, __shfl_xor(m, 16));
      m = fmaxf(m, __shfl_xor(m, 32));
      float mnew = fmaxf(mrun[mi], m);
      float alpha = exp2f((mrun[mi] - mnew) * LOG2E);
      mrun[mi] = mnew;
      float rs0 = 0.f;
#pragma unroll
      for (int ni = 0; ni < 8; ni++)
#pragma unroll
        for (int r = 0; r < 4; r++) {
          float p = exp2f((st[mi][ni][r] - mnew) * LOG2E);
          st[mi][ni][r] = p;
          rs0 += p;
        }
      rs0 += __shfl_xor(rs0, 16);
      rs0 += __shfl_xor(rs0, 32);
      lrun[mi] = lrun[mi] * alpha + rs0;
#pragma unroll
      for (int dv = 0; dv < 4; dv++) {
        oacc[mi][dv][0] *= alpha; oacc[mi][dv][1] *= alpha;
        oacc[mi][dv][2] *= alpha; oacc[mi][dv][3] *= alpha;
      }
    }

    // PV: O^T += V^T x P^T, 32-key slices
#pragma unroll
    for (int kc = 0; kc < 4; kc++) {
      bf16x8 vf[4];
#pragma unroll
      for (int dv = 0; dv < 4; dv++) {
        int d = dv * 16 + l15;
        vf[dv] = *(const bf16x8*)(Vsm + d * 256 + (((kc * 4 + l4) ^ l15) * 16));
      }
#pragma unroll
      for (int mi = 0; mi < 2; mi++) {
#pragma unroll
        for (int n = 0; n < 2; n++) {
          f32x4 pv = st[mi][kc * 2 + n];
          bf16x4 pk = {(bf16)pv[0], (bf16)pv[1], (bf16)pv[2], (bf16)pv[3]};
          *(bf16x4*)(Pw + l15 * 80 + n * 32 + l4 * 8) = pk;
        }
        bf16x8 pf = *(const bf16x8*)(Pw + l15 * 80 + l4 * 16);
#pragma unroll
        for (int dv = 0; dv < 4; dv++)
          oacc[mi][dv] = MFMA16(vf[dv], pf, oacc[mi][dv]);
      }
    }
  }

  // epilogue: O[q][d] with 8B packed stores (d contiguous over r)
#pragma unroll
  for (int mi = 0; mi < 2; mi++) {
    float inv = 1.0f / lrun[mi];
    size_t grow = qrow0 + wid * 32 + mi * 16 + l15;
#pragma unroll
    for (int dv = 0; dv < 4; dv++) {
      f32x4 o = oacc[mi][dv];
      bf16x4 ob = {(bf16)(o[0] * inv), (bf16)(o[1] * inv), (bf16)(o[2] * inv), (bf16)(o[3] * inv)};
      *(bf16x4*)(O + grow * HD + colh + dv * 16 + l4 * 4) = ob;
    }
  }
}

extern "C" void kernel_launch(void* const* d_in, const int* in_sizes, int n_in,
                              void* d_out, int out_size, void* d_ws, size_t ws_size,
                              hipStream_t stream) {
  const float* hs = (const float*)d_in[0];
  const float* Wq = (const float*)d_in[1];
  const float* Wk = (const float*)d_in[2];
  const float* Wv = (const float*)d_in[3];
  const float* Wo = (const float*)d_in[4];
  float* out = (float*)d_out;

  char* ws = (char*)d_ws;
  const size_t MB = 1u << 20;
  bf16* Xb = (bf16*)(ws);                 // 16 MB, reused as attention output
  bf16* Qb = (bf16*)(ws + 16 * MB);
  bf16* Kb = (bf16*)(ws + 32 * MB);
  bf16* Vt = (bf16*)(ws + 48 * MB);       // V^T [64 bh][64 d][2048 s]
  bf16* Wtq = (bf16*)(ws + 64 * MB);
  bf16* Wtk = Wtq + 512 * 512;
  bf16* Wtv = Wtk + 512 * 512;
  bf16* Wto = Wtv + 512 * 512;
  float2* ctab = (float2*)(ws + 64 * MB + 4 * 512 * 512 * sizeof(bf16));
  bf16* AO = Xb;

  k_conv<<<dim3(Mrows * DM / (256 * 8)), dim3(256), 0, stream>>>(hs, Xb);
  k_transw<<<dim3(16, 16), dim3(32, 8), 0, stream>>>(Wq, Wtq);
  k_transw<<<dim3(16, 16), dim3(32, 8), 0, stream>>>(Wk, Wtk);
  k_transw<<<dim3(16, 16), dim3(32, 8), 0, stream>>>(Wv, Wtv);
  k_transw<<<dim3(16, 16), dim3(32, 8), 0, stream>>>(Wo, Wto);
  k_ctab<<<dim3(S * 32 / 256), dim3(256), 0, stream>>>(ctab);
  k_gemm_qkv<<<dim3(Mrows / 128, 4, 3), dim3(256), 0, stream>>>(Xb, Wtq, Wtk, Wtv, Qb, Kb, Vt, ctab);
  k_attn<<<dim3(NBLK, H, 8), dim3(256), 0, stream>>>(Qb, Kb, Vt, AO);
  k_gemm_out<<<dim3(Mrows / 128, 4), dim3(256), 0, stream>>>(AO, Wto, out);
}

// Round 4
// 124.651 us; speedup vs baseline: 1.4204x; 1.2171x over previous
//
#include <hip/hip_runtime.h>

using bf16 = __bf16;
typedef __bf16 bf16x8 __attribute__((ext_vector_type(8)));
typedef __bf16 bf16x4 __attribute__((ext_vector_type(4)));
typedef float f32x4 __attribute__((ext_vector_type(4)));
typedef float f32x16 __attribute__((ext_vector_type(16)));

#define MFMA16(a, b, c) __builtin_amdgcn_mfma_f32_16x16x32_bf16((a), (b), (c), 0, 0, 0)
#define MFMA32(a, b, c) __builtin_amdgcn_mfma_f32_32x32x16_bf16((a), (b), (c), 0, 0, 0)

constexpr int S = 2048, DM = 512, H = 8, DK = 64, HD = 512;
constexpr int NBLK = 16, BLK = 128;
constexpr int Mrows = 8 * S;  // 16384
constexpr float LOG2E = 1.44269504088896340736f;

__device__ __forceinline__ void gll16(const void* g, void* l) {
  __builtin_amdgcn_global_load_lds((const __attribute__((address_space(1))) unsigned int*)g,
                                   (__attribute__((address_space(3))) unsigned int*)l, 16, 0, 0);
}

// ---------------- fp32 -> bf16 convert (hidden) ----------------
__global__ void k_conv(const float* __restrict__ x, bf16* __restrict__ y) {
  size_t i = ((size_t)blockIdx.x * 256 + threadIdx.x) * 8;
  float4 a = *(const float4*)(x + i);
  float4 b = *(const float4*)(x + i + 4);
  bf16x8 o;
  o[0] = (bf16)a.x; o[1] = (bf16)a.y; o[2] = (bf16)a.z; o[3] = (bf16)a.w;
  o[4] = (bf16)b.x; o[5] = (bf16)b.y; o[6] = (bf16)b.z; o[7] = (bf16)b.w;
  *(bf16x8*)(y + i) = o;
}

// ---------------- weight transpose + convert (all 4 weights, z-indexed) ----------------
__global__ void k_transw4(const float* __restrict__ W0, const float* __restrict__ W1,
                          const float* __restrict__ W2, const float* __restrict__ W3,
                          bf16* __restrict__ D0, bf16* __restrict__ D1,
                          bf16* __restrict__ D2, bf16* __restrict__ D3) {
  const int z = blockIdx.z;
  const float* W = (z == 0) ? W0 : (z == 1) ? W1 : (z == 2) ? W2 : W3;
  bf16* Wt = (z == 0) ? D0 : (z == 1) ? D1 : (z == 2) ? D2 : D3;
  __shared__ float tile[32][33];
  int k0 = blockIdx.x * 32, n0 = blockIdx.y * 32;
  int tx = threadIdx.x, ty = threadIdx.y;  // (32,8)
#pragma unroll
  for (int i = 0; i < 4; i++)
    tile[ty * 4 + i][tx] = W[(size_t)(k0 + ty * 4 + i) * 512 + n0 + tx];
  __syncthreads();
#pragma unroll
  for (int i = 0; i < 4; i++)
    Wt[(size_t)(n0 + ty * 4 + i) * 512 + k0 + tx] = (bf16)tile[tx][ty * 4 + i];
}

// ---------------- RoPE cos/sin table ----------------
__global__ void k_ctab(float2* __restrict__ ctab) {
  int idx = blockIdx.x * 256 + threadIdx.x;  // 65536 entries
  int s = idx >> 5, i = idx & 31;
  float invf = exp2f(-(float)i * (13.287712379549449f / 32.0f));  // 10000^(-i/32)
  float ang = (float)s * invf;
  ctab[idx] = make_float2(cosf(ang), sinf(ang));
}

// ---------------- 128x128x(K=512) bf16 GEMM, QKV variant with fused RoPE ----------------
// z=0: Q (rope, *LOG2E) -> Qo flat.  z=1: K (rope) -> Ko flat.  z=2: V -> Vt[bh][d][s].
__global__ __launch_bounds__(256) void k_gemm_qkv(
    const bf16* __restrict__ Xb,
    const bf16* __restrict__ Wtq, const bf16* __restrict__ Wtk, const bf16* __restrict__ Wtv,
    bf16* __restrict__ Qo, bf16* __restrict__ Ko, bf16* __restrict__ Vt,
    const float2* __restrict__ ctab) {
  const int z = blockIdx.z;
  const bf16* Wt = (z == 0) ? Wtq : ((z == 1) ? Wtk : Wtv);
  bf16* dst = (z == 0) ? Qo : Ko;
  const float qscale = (z == 0) ? LOG2E : 1.0f;

  __shared__ __align__(16) char Asm[128 * 64];  // 128 rows x 32 bf16, 16B-chunk XOR swizzle
  __shared__ __align__(16) char Bsm[128 * 64];

  const int t = threadIdx.x, l = t & 63, wid = t >> 6;
  const int l15 = l & 15, l4 = l >> 4;
  const int wm = wid >> 1, wn = wid & 1;
  const size_t arow0 = (size_t)blockIdx.x * 128;
  const size_t brow0 = (size_t)blockIdx.y * 128;

  f32x4 acc[4][4] = {};
  const int rs = wid * 16 + (l >> 2);          // linear dest row (issue 0)
  const int cs = (l & 3) ^ ((l >> 2) & 3);     // pre-swizzled source chunk

  for (int kt = 0; kt < 16; ++kt) {
    const int k0 = kt * 32;
    __syncthreads();
    gll16(Xb + (arow0 + rs) * 512 + k0 + cs * 8,      Asm + wid * 1024);
    gll16(Xb + (arow0 + 64 + rs) * 512 + k0 + cs * 8, Asm + 4096 + wid * 1024);
    gll16(Wt + (brow0 + rs) * 512 + k0 + cs * 8,      Bsm + wid * 1024);
    gll16(Wt + (brow0 + 64 + rs) * 512 + k0 + cs * 8, Bsm + 4096 + wid * 1024);
    __syncthreads();
    bf16x8 af[4], bfr[4];
#pragma unroll
    for (int mi = 0; mi < 4; mi++) {
      int row = wm * 64 + mi * 16 + l15;
      af[mi] = *(const bf16x8*)(Asm + row * 64 + ((l4 ^ (row & 3)) * 16));
    }
#pragma unroll
    for (int ni = 0; ni < 4; ni++) {
      int row = wn * 64 + ni * 16 + l15;
      bfr[ni] = *(const bf16x8*)(Bsm + row * 64 + ((l4 ^ (row & 3)) * 16));
    }
#pragma unroll
    for (int mi = 0; mi < 4; mi++)
#pragma unroll
      for (int ni = 0; ni < 4; ni++)
        acc[mi][ni] = MFMA16(af[mi], bfr[ni], acc[mi][ni]);
  }

  if (z == 2) {
    // write V^T: Vt[(b*H + h)*64 + d][s], pack 4 consecutive s (r dim) per store
    const int b = (int)(arow0 >> 11);
#pragma unroll
    for (int mi = 0; mi < 4; mi++) {
      int scol = (int)(arow0 & 2047) + wm * 64 + mi * 16 + l4 * 4;
#pragma unroll
      for (int ni = 0; ni < 4; ni++) {
        int col = (int)brow0 + wn * 64 + ni * 16 + l15;
        int hh = col >> 6, dd = col & 63;
        bf16x4 pk = {(bf16)acc[mi][ni][0], (bf16)acc[mi][ni][1],
                     (bf16)acc[mi][ni][2], (bf16)acc[mi][ni][3]};
        *(bf16x4*)(Vt + ((size_t)((b * H + hh) * 64 + dd)) * 2048 + scol) = pk;
      }
    }
    return;
  }

#pragma unroll
  for (int mi = 0; mi < 4; mi++) {
#pragma unroll
    for (int r = 0; r < 4; r++) {
      int grow = (int)arow0 + wm * 64 + mi * 16 + l4 * 4 + r;
      size_t rowoff = (size_t)grow * 512 + brow0 + wn * 64;
      int s = grow & (S - 1);
      float2 cs0 = ctab[s * 32 + l15];
      float2 cs1 = ctab[s * 32 + 16 + l15];
#pragma unroll
      for (int ni = 0; ni < 4; ni++) {
        float a = acc[mi][ni][r];
        float b = acc[mi][ni ^ 2][r];
        float2 cc = (ni & 1) ? cs1 : cs0;
        float val = (ni < 2) ? (a * cc.x - b * cc.y) : (a * cc.x + b * cc.y);
        dst[rowoff + ni * 16 + l15] = (bf16)(val * qscale);
      }
    }
  }
}

// ---------------- output projection GEMM -> fp32 ----------------
__global__ __launch_bounds__(256) void k_gemm_out(
    const bf16* __restrict__ A, const bf16* __restrict__ Wt, float* __restrict__ out) {
  __shared__ __align__(16) char Asm[128 * 64];
  __shared__ __align__(16) char Bsm[128 * 64];

  const int t = threadIdx.x, l = t & 63, wid = t >> 6;
  const int l15 = l & 15, l4 = l >> 4;
  const int wm = wid >> 1, wn = wid & 1;
  const size_t arow0 = (size_t)blockIdx.x * 128;
  const size_t brow0 = (size_t)blockIdx.y * 128;

  f32x4 acc[4][4] = {};
  const int rs = wid * 16 + (l >> 2);
  const int cs = (l & 3) ^ ((l >> 2) & 3);

  for (int kt = 0; kt < 16; ++kt) {
    const int k0 = kt * 32;
    __syncthreads();
    gll16(A + (arow0 + rs) * 512 + k0 + cs * 8,       Asm + wid * 1024);
    gll16(A + (arow0 + 64 + rs) * 512 + k0 + cs * 8,  Asm + 4096 + wid * 1024);
    gll16(Wt + (brow0 + rs) * 512 + k0 + cs * 8,      Bsm + wid * 1024);
    gll16(Wt + (brow0 + 64 + rs) * 512 + k0 + cs * 8, Bsm + 4096 + wid * 1024);
    __syncthreads();
    bf16x8 af[4], bfr[4];
#pragma unroll
    for (int mi = 0; mi < 4; mi++) {
      int row = wm * 64 + mi * 16 + l15;
      af[mi] = *(const bf16x8*)(Asm + row * 64 + ((l4 ^ (row & 3)) * 16));
    }
#pragma unroll
    for (int ni = 0; ni < 4; ni++) {
      int row = wn * 64 + ni * 16 + l15;
      bfr[ni] = *(const bf16x8*)(Bsm + row * 64 + ((l4 ^ (row & 3)) * 16));
    }
#pragma unroll
    for (int mi = 0; mi < 4; mi++)
#pragma unroll
      for (int ni = 0; ni < 4; ni++)
        acc[mi][ni] = MFMA16(af[mi], bfr[ni], acc[mi][ni]);
  }

#pragma unroll
  for (int mi = 0; mi < 4; mi++)
#pragma unroll
    for (int r = 0; r < 4; r++) {
      int grow = (int)arow0 + wm * 64 + mi * 16 + l4 * 4 + r;
      size_t rowoff = (size_t)grow * 512 + brow0 + wn * 64;
#pragma unroll
      for (int ni = 0; ni < 4; ni++)
        out[rowoff + ni * 16 + l15] = acc[mi][ni][r];
    }
}

// ---------------- block-banded flash attention: register-only, 32x32 MFMA ----------------
// grid (16, 8, 8), 256 thr = 4 waves x 32 q-rows. Wave w processes key chunks c = w..w+8.
// All operands read directly from global (L2-resident); P^T fragments built in-register
// via cvt_pk + half-wave exchange (shfl_xor 32). Q pre-scaled by LOG2E (exp2 domain).
__global__ __launch_bounds__(256) void k_attn(
    const bf16* __restrict__ Q, const bf16* __restrict__ K, const bf16* __restrict__ Vt,
    bf16* __restrict__ O) {
  const int nb = blockIdx.x, h = blockIdx.y, bb = blockIdx.z;
  const int t = threadIdx.x, l = t & 63, w = t >> 6;
  const int q31 = l & 31, hi = l >> 5;

  const int bh = bb * H + h;
  const size_t qrow = (size_t)bb * S + nb * BLK + w * 32 + q31;

  // Q B-frags: col q = l&31, k(dk) = ks*16 + hi*8 + j
  const bf16* Qp = Q + qrow * HD + h * DK + hi * 8;
  bf16x8 qb[4];
#pragma unroll
  for (int ks = 0; ks < 4; ks++) qb[ks] = *(const bf16x8*)(Qp + ks * 16);

  f32x16 o0 = {}, o1 = {};  // O^T[d][q]: q = l&31, d = dt*32 + (rg&3)+8*(rg>>2)+4*hi
  float mrun = -3e38f, lrun = 0.f;

  const bf16* Kbase = K + (size_t)bb * S * HD + h * DK + hi * 8;
  const bf16* Vbase = Vt + ((size_t)bh * 64 + q31) * 2048 + hi * 8;

  for (int cr = 0; cr < 9; ++cr) {
    const int kg0 = nb * BLK + (w + cr) * 32 - 128;  // global key of chunk start
    if (kg0 < 0 || kg0 >= S) continue;               // whole chunk in/out (32-aligned)

    // K A-frags: row key = kg0 + (l&31), k(dk) = ks*16 + hi*8 + j
    const bf16* Kp = Kbase + (size_t)(kg0 + q31) * HD;
    bf16x8 ka0 = *(const bf16x8*)(Kp);
    bf16x8 ka1 = *(const bf16x8*)(Kp + 16);
    bf16x8 ka2 = *(const bf16x8*)(Kp + 32);
    bf16x8 ka3 = *(const bf16x8*)(Kp + 48);
    // V^T A-frags: row d = dt*32 + (l&31), k(key) = kg0 + ks2*16 + hi*8 + j
    const bf16* Vp = Vbase + kg0;
    bf16x8 va00 = *(const bf16x8*)(Vp);
    bf16x8 va01 = *(const bf16x8*)(Vp + 16);
    bf16x8 va10 = *(const bf16x8*)(Vp + 32 * 2048);
    bf16x8 va11 = *(const bf16x8*)(Vp + 32 * 2048 + 16);

    f32x16 acc = {};
    acc = MFMA32(ka0, qb[0], acc);
    acc = MFMA32(ka1, qb[1], acc);
    acc = MFMA32(ka2, qb[2], acc);
    acc = MFMA32(ka3, qb[3], acc);

    // band mask: only first/last chunk of each wave's window needs the triangle
    if (cr == 0) {
#pragma unroll
      for (int rg = 0; rg < 16; rg++) {
        int kk = (rg & 3) + 8 * (rg >> 2) + 4 * hi;
        if (kk < q31) acc[rg] = -1e30f;  // valid iff kk >= qq
      }
    } else if (cr == 8) {
#pragma unroll
      for (int rg = 0; rg < 16; rg++) {
        int kk = (rg & 3) + 8 * (rg >> 2) + 4 * hi;
        if (kk > q31) acc[rg] = -1e30f;  // valid iff kk <= qq
      }
    }

    // online softmax (exp2 domain), keys split in-lane(16) x lane-halves(2)
    float m = acc[0];
#pragma unroll
    for (int rg = 1; rg < 16; rg++) m = fmaxf(m, acc[rg]);
    m = fmaxf(m, __shfl_xor(m, 32));
    const float mnew = fmaxf(mrun, m);
    const float alpha = exp2f(mrun - mnew);
    mrun = mnew;
    float p[16];
    float rs = 0.f;
#pragma unroll
    for (int rg = 0; rg < 16; rg++) {
      p[rg] = exp2f(acc[rg] - mnew);
      rs += p[rg];
    }
    rs += __shfl_xor(rs, 32);
    lrun = lrun * alpha + rs;
#pragma unroll
    for (int rg = 0; rg < 16; rg++) { o0[rg] *= alpha; o1[rg] *= alpha; }

    // P^T B-frags in-register: cvt_pk words then half-wave exchange via shfl_xor(32).
    // Wd[a][b] (this lane, half hi) = keys 8a + 4hi + 2b, +1  (col q31).
    // Fragment ks word u[b] = keys 16ks + 8hi + 2b; u[2+b] = keys 16ks + 8hi + 4 + 2b.
    unsigned int Wd[4][2];
#pragma unroll
    for (int a = 0; a < 4; a++)
#pragma unroll
      for (int b2 = 0; b2 < 2; b2++) {
        unsigned int wd;
        asm("v_cvt_pk_bf16_f32 %0, %1, %2" : "=v"(wd) : "v"(p[4 * a + 2 * b2]), "v"(p[4 * a + 2 * b2 + 1]));
        Wd[a][b2] = wd;
      }
    bf16x8 pf[2];
#pragma unroll
    for (int ks = 0; ks < 2; ks++) {
      union { unsigned int u[4]; bf16x8 v; } cvt;
#pragma unroll
      for (int b2 = 0; b2 < 2; b2++) {
        unsigned int low_w = Wd[2 * ks][b2];      // keys 16ks + 4hi + 2b
        unsigned int hi_w  = Wd[2 * ks + 1][b2];  // keys 16ks + 8 + 4hi + 2b
        unsigned int msg = hi ? low_w : hi_w;     // send what the other half needs
        unsigned int rec = __shfl_xor(msg, 32);
        cvt.u[b2]     = hi ? rec : low_w;         // keys 16ks + 8hi + 2b
        cvt.u[2 + b2] = hi ? hi_w : rec;          // keys 16ks + 8hi + 4 + 2b
      }
      pf[ks] = cvt.v;
    }

    o0 = MFMA32(va00, pf[0], o0);
    o0 = MFMA32(va01, pf[1], o0);
    o1 = MFMA32(va10, pf[0], o1);
    o1 = MFMA32(va11, pf[1], o1);
  }

  const float inv = 1.0f / lrun;
  bf16* Op = O + qrow * HD + h * DK + 4 * hi;
#pragma unroll
  for (int dt = 0; dt < 2; dt++) {
    const f32x16 oo = dt ? o1 : o0;
#pragma unroll
    for (int a = 0; a < 4; a++) {
      bf16x4 ob = {(bf16)(oo[4 * a + 0] * inv), (bf16)(oo[4 * a + 1] * inv),
                   (bf16)(oo[4 * a + 2] * inv), (bf16)(oo[4 * a + 3] * inv)};
      *(bf16x4*)(Op + dt * 32 + 8 * a) = ob;  // d = dt*32 + 8a + 4hi + (0..3)
    }
  }
}

extern "C" void kernel_launch(void* const* d_in, const int* in_sizes, int n_in,
                              void* d_out, int out_size, void* d_ws, size_t ws_size,
                              hipStream_t stream) {
  const float* hs = (const float*)d_in[0];
  const float* Wq = (const float*)d_in[1];
  const float* Wk = (const float*)d_in[2];
  const float* Wv = (const float*)d_in[3];
  const float* Wo = (const float*)d_in[4];
  float* out = (float*)d_out;

  char* ws = (char*)d_ws;
  const size_t MB = 1u << 20;
  bf16* Xb = (bf16*)(ws);                 // 16 MB, reused as attention output
  bf16* Qb = (bf16*)(ws + 16 * MB);
  bf16* Kb = (bf16*)(ws + 32 * MB);
  bf16* Vt = (bf16*)(ws + 48 * MB);       // V^T [64 bh][64 d][2048 s]
  bf16* Wtq = (bf16*)(ws + 64 * MB);
  bf16* Wtk = Wtq + 512 * 512;
  bf16* Wtv = Wtk + 512 * 512;
  bf16* Wto = Wtv + 512 * 512;
  float2* ctab = (float2*)(ws + 64 * MB + 4 * 512 * 512 * sizeof(bf16));
  bf16* AO = Xb;

  k_conv<<<dim3(Mrows * DM / (256 * 8)), dim3(256), 0, stream>>>(hs, Xb);
  k_transw4<<<dim3(16, 16, 4), dim3(32, 8), 0, stream>>>(Wq, Wk, Wv, Wo, Wtq, Wtk, Wtv, Wto);
  k_ctab<<<dim3(S * 32 / 256), dim3(256), 0, stream>>>(ctab);
  k_gemm_qkv<<<dim3(Mrows / 128, 4, 3), dim3(256), 0, stream>>>(Xb, Wtq, Wtk, Wtv, Qb, Kb, Vt, ctab);
  k_attn<<<dim3(NBLK, H, 8), dim3(256), 0, stream>>>(Qb, Kb, Vt, AO);
  k_gemm_out<<<dim3(Mrows / 128, 4), dim3(256), 0, stream>>>(AO, Wto, out);
}

// Round 5
// 117.228 us; speedup vs baseline: 1.5103x; 1.0633x over previous
//
#include <hip/hip_runtime.h>

using bf16 = __bf16;
typedef __bf16 bf16x8 __attribute__((ext_vector_type(8)));
typedef __bf16 bf16x4 __attribute__((ext_vector_type(4)));
typedef float f32x4 __attribute__((ext_vector_type(4)));
typedef float f32x16 __attribute__((ext_vector_type(16)));

#define MFMA16(a, b, c) __builtin_amdgcn_mfma_f32_16x16x32_bf16((a), (b), (c), 0, 0, 0)
#define MFMA32(a, b, c) __builtin_amdgcn_mfma_f32_32x32x16_bf16((a), (b), (c), 0, 0, 0)

constexpr int S = 2048, DM = 512, H = 8, DK = 64, HD = 512;
constexpr int NBLK = 16, BLK = 128;
constexpr int Mrows = 8 * S;  // 16384
constexpr float LOG2E = 1.44269504088896340736f;

__device__ __forceinline__ void gll16(const void* g, void* l) {
  __builtin_amdgcn_global_load_lds((const __attribute__((address_space(1))) unsigned int*)g,
                                   (__attribute__((address_space(3))) unsigned int*)l, 16, 0, 0);
}

// ---------------- fp32 -> bf16 convert (hidden) ----------------
__global__ void k_conv(const float* __restrict__ x, bf16* __restrict__ y) {
  size_t i = ((size_t)blockIdx.x * 256 + threadIdx.x) * 8;
  float4 a = *(const float4*)(x + i);
  float4 b = *(const float4*)(x + i + 4);
  bf16x8 o;
  o[0] = (bf16)a.x; o[1] = (bf16)a.y; o[2] = (bf16)a.z; o[3] = (bf16)a.w;
  o[4] = (bf16)b.x; o[5] = (bf16)b.y; o[6] = (bf16)b.z; o[7] = (bf16)b.w;
  *(bf16x8*)(y + i) = o;
}

// ---------------- weight transpose + convert (all 4 weights, z-indexed) ----------------
__global__ void k_transw4(const float* __restrict__ W0, const float* __restrict__ W1,
                          const float* __restrict__ W2, const float* __restrict__ W3,
                          bf16* __restrict__ D0, bf16* __restrict__ D1,
                          bf16* __restrict__ D2, bf16* __restrict__ D3) {
  const int z = blockIdx.z;
  const float* W = (z == 0) ? W0 : (z == 1) ? W1 : (z == 2) ? W2 : W3;
  bf16* Wt = (z == 0) ? D0 : (z == 1) ? D1 : (z == 2) ? D2 : D3;
  __shared__ float tile[32][33];
  int k0 = blockIdx.x * 32, n0 = blockIdx.y * 32;
  int tx = threadIdx.x, ty = threadIdx.y;  // (32,8)
#pragma unroll
  for (int i = 0; i < 4; i++)
    tile[ty * 4 + i][tx] = W[(size_t)(k0 + ty * 4 + i) * 512 + n0 + tx];
  __syncthreads();
#pragma unroll
  for (int i = 0; i < 4; i++)
    Wt[(size_t)(n0 + ty * 4 + i) * 512 + k0 + tx] = (bf16)tile[tx][ty * 4 + i];
}

// ---------------- RoPE cos/sin table ----------------
__global__ void k_ctab(float2* __restrict__ ctab) {
  int idx = blockIdx.x * 256 + threadIdx.x;  // 65536 entries
  int s = idx >> 5, i = idx & 31;
  float invf = exp2f(-(float)i * (13.287712379549449f / 32.0f));  // 10000^(-i/32)
  float ang = (float)s * invf;
  ctab[idx] = make_float2(cosf(ang), sinf(ang));
}

// ---------------- 128x128x(K=512) bf16 GEMM, QKV variant with fused RoPE ----------------
// z=0: Q (rope, *LOG2E) -> Qo flat.  z=1: K (rope) -> Ko flat.  z=2: V -> Vt[bh][d][s].
__global__ __launch_bounds__(256) void k_gemm_qkv(
    const bf16* __restrict__ Xb,
    const bf16* __restrict__ Wtq, const bf16* __restrict__ Wtk, const bf16* __restrict__ Wtv,
    bf16* __restrict__ Qo, bf16* __restrict__ Ko, bf16* __restrict__ Vt,
    const float2* __restrict__ ctab) {
  const int z = blockIdx.z;
  const bf16* Wt = (z == 0) ? Wtq : ((z == 1) ? Wtk : Wtv);
  bf16* dst = (z == 0) ? Qo : Ko;
  const float qscale = (z == 0) ? LOG2E : 1.0f;

  __shared__ __align__(16) char Asm[128 * 64];  // 128 rows x 32 bf16, 16B-chunk XOR swizzle
  __shared__ __align__(16) char Bsm[128 * 64];

  const int t = threadIdx.x, l = t & 63, wid = t >> 6;
  const int l15 = l & 15, l4 = l >> 4;
  const int wm = wid >> 1, wn = wid & 1;
  const size_t arow0 = (size_t)blockIdx.x * 128;
  const size_t brow0 = (size_t)blockIdx.y * 128;

  f32x4 acc[4][4] = {};
  const int rs = wid * 16 + (l >> 2);          // linear dest row (issue 0)
  const int cs = (l & 3) ^ ((l >> 2) & 3);     // pre-swizzled source chunk

  for (int kt = 0; kt < 16; ++kt) {
    const int k0 = kt * 32;
    __syncthreads();
    gll16(Xb + (arow0 + rs) * 512 + k0 + cs * 8,      Asm + wid * 1024);
    gll16(Xb + (arow0 + 64 + rs) * 512 + k0 + cs * 8, Asm + 4096 + wid * 1024);
    gll16(Wt + (brow0 + rs) * 512 + k0 + cs * 8,      Bsm + wid * 1024);
    gll16(Wt + (brow0 + 64 + rs) * 512 + k0 + cs * 8, Bsm + 4096 + wid * 1024);
    __syncthreads();
    bf16x8 af[4], bfr[4];
#pragma unroll
    for (int mi = 0; mi < 4; mi++) {
      int row = wm * 64 + mi * 16 + l15;
      af[mi] = *(const bf16x8*)(Asm + row * 64 + ((l4 ^ (row & 3)) * 16));
    }
#pragma unroll
    for (int ni = 0; ni < 4; ni++) {
      int row = wn * 64 + ni * 16 + l15;
      bfr[ni] = *(const bf16x8*)(Bsm + row * 64 + ((l4 ^ (row & 3)) * 16));
    }
#pragma unroll
    for (int mi = 0; mi < 4; mi++)
#pragma unroll
      for (int ni = 0; ni < 4; ni++)
        acc[mi][ni] = MFMA16(af[mi], bfr[ni], acc[mi][ni]);
  }

  if (z == 2) {
    // write V^T: Vt[(b*H + h)*64 + d][s], pack 4 consecutive s (r dim) per store
    const int b = (int)(arow0 >> 11);
#pragma unroll
    for (int mi = 0; mi < 4; mi++) {
      int scol = (int)(arow0 & 2047) + wm * 64 + mi * 16 + l4 * 4;
#pragma unroll
      for (int ni = 0; ni < 4; ni++) {
        int col = (int)brow0 + wn * 64 + ni * 16 + l15;
        int hh = col >> 6, dd = col & 63;
        bf16x4 pk = {(bf16)acc[mi][ni][0], (bf16)acc[mi][ni][1],
                     (bf16)acc[mi][ni][2], (bf16)acc[mi][ni][3]};
        *(bf16x4*)(Vt + ((size_t)((b * H + hh) * 64 + dd)) * 2048 + scol) = pk;
      }
    }
    return;
  }

#pragma unroll
  for (int mi = 0; mi < 4; mi++) {
#pragma unroll
    for (int r = 0; r < 4; r++) {
      int grow = (int)arow0 + wm * 64 + mi * 16 + l4 * 4 + r;
      size_t rowoff = (size_t)grow * 512 + brow0 + wn * 64;
      int s = grow & (S - 1);
      float2 cs0 = ctab[s * 32 + l15];
      float2 cs1 = ctab[s * 32 + 16 + l15];
#pragma unroll
      for (int ni = 0; ni < 4; ni++) {
        float a = acc[mi][ni][r];
        float b = acc[mi][ni ^ 2][r];
        float2 cc = (ni & 1) ? cs1 : cs0;
        float val = (ni < 2) ? (a * cc.x - b * cc.y) : (a * cc.x + b * cc.y);
        dst[rowoff + ni * 16 + l15] = (bf16)(val * qscale);
      }
    }
  }
}

// ---------------- output projection GEMM -> fp32 ----------------
__global__ __launch_bounds__(256) void k_gemm_out(
    const bf16* __restrict__ A, const bf16* __restrict__ Wt, float* __restrict__ out) {
  __shared__ __align__(16) char Asm[128 * 64];
  __shared__ __align__(16) char Bsm[128 * 64];

  const int t = threadIdx.x, l = t & 63, wid = t >> 6;
  const int l15 = l & 15, l4 = l >> 4;
  const int wm = wid >> 1, wn = wid & 1;
  const size_t arow0 = (size_t)blockIdx.x * 128;
  const size_t brow0 = (size_t)blockIdx.y * 128;

  f32x4 acc[4][4] = {};
  const int rs = wid * 16 + (l >> 2);
  const int cs = (l & 3) ^ ((l >> 2) & 3);

  for (int kt = 0; kt < 16; ++kt) {
    const int k0 = kt * 32;
    __syncthreads();
    gll16(A + (arow0 + rs) * 512 + k0 + cs * 8,       Asm + wid * 1024);
    gll16(A + (arow0 + 64 + rs) * 512 + k0 + cs * 8,  Asm + 4096 + wid * 1024);
    gll16(Wt + (brow0 + rs) * 512 + k0 + cs * 8,      Bsm + wid * 1024);
    gll16(Wt + (brow0 + 64 + rs) * 512 + k0 + cs * 8, Bsm + 4096 + wid * 1024);
    __syncthreads();
    bf16x8 af[4], bfr[4];
#pragma unroll
    for (int mi = 0; mi < 4; mi++) {
      int row = wm * 64 + mi * 16 + l15;
      af[mi] = *(const bf16x8*)(Asm + row * 64 + ((l4 ^ (row & 3)) * 16));
    }
#pragma unroll
    for (int ni = 0; ni < 4; ni++) {
      int row = wn * 64 + ni * 16 + l15;
      bfr[ni] = *(const bf16x8*)(Bsm + row * 64 + ((l4 ^ (row & 3)) * 16));
    }
#pragma unroll
    for (int mi = 0; mi < 4; mi++)
#pragma unroll
      for (int ni = 0; ni < 4; ni++)
        acc[mi][ni] = MFMA16(af[mi], bfr[ni], acc[mi][ni]);
  }

#pragma unroll
  for (int mi = 0; mi < 4; mi++)
#pragma unroll
    for (int r = 0; r < 4; r++) {
      int grow = (int)arow0 + wm * 64 + mi * 16 + l4 * 4 + r;
      size_t rowoff = (size_t)grow * 512 + brow0 + wn * 64;
#pragma unroll
      for (int ni = 0; ni < 4; ni++)
        out[rowoff + ni * 16 + l15] = acc[mi][ni][r];
    }
}

// ---------------- block-banded flash attention: register-only, 32x32 MFMA ----------------
// 1024 blocks (XCD-swizzled), 256 thr = 4 waves x 32 q-rows. 5 softmax steps of 64/32 keys.
// Operands direct from global (L2-resident); P^T built in-register (cvt_pk + shfl_xor 32).
// Q pre-scaled by LOG2E (exp2 domain). Defer-max: skip rescale unless max grows by >8.
__global__ __launch_bounds__(256, 4) void k_attn(
    const bf16* __restrict__ Q, const bf16* __restrict__ K, const bf16* __restrict__ Vt,
    bf16* __restrict__ O) {
  // XCD swizzle: XCD x owns logical ids [x*128, x*128+128) = one full batch
  const int bid = blockIdx.x;
  const int swz = (bid & 7) * 128 + (bid >> 3);
  const int nb = swz & 15, h = (swz >> 4) & 7, bb = swz >> 7;
  const int t = threadIdx.x, l = t & 63, w = t >> 6;
  const int q31 = l & 31, hi = l >> 5;

  const int bh = bb * H + h;
  const size_t qrow = (size_t)bb * S + nb * BLK + w * 32 + q31;

  // Q B-frags: col q = l&31, k(dk) = ks*16 + hi*8 + j
  const bf16* Qp = Q + qrow * HD + h * DK + hi * 8;
  bf16x8 qb[4];
#pragma unroll
  for (int ks = 0; ks < 4; ks++) qb[ks] = *(const bf16x8*)(Qp + ks * 16);

  f32x16 o0 = {}, o1 = {};  // O^T[d][q]: q = l&31, d = dt*32 + (rg&3)+8*(rg>>2)+4*hi
  float mrun = -3e38f, lrun = 0.f;

  const bf16* Kbase = K + (size_t)bb * S * HD + h * DK + hi * 8;
  const bf16* Vbase = Vt + ((size_t)bh * 64 + q31) * 2048 + hi * 8;
  const int s0 = nb * BLK + w * 32 - 128;  // window start (chunk 0), 9 chunks of 32

  // PV helper: convert 16 in-lane p's (one 32-key chunk) to P^T B-frags and MFMA with V^T.
  auto pv = [&](const f32x16& p, int kgc) {
    unsigned int Wd[4][2];
#pragma unroll
    for (int a = 0; a < 4; a++)
#pragma unroll
      for (int b2 = 0; b2 < 2; b2++) {
        unsigned int wd;
        asm("v_cvt_pk_bf16_f32 %0, %1, %2" : "=v"(wd) : "v"(p[4 * a + 2 * b2]), "v"(p[4 * a + 2 * b2 + 1]));
        Wd[a][b2] = wd;
      }
    bf16x8 pf[2];
#pragma unroll
    for (int ks = 0; ks < 2; ks++) {
      union { unsigned int u[4]; bf16x8 v; } cvt;
#pragma unroll
      for (int b2 = 0; b2 < 2; b2++) {
        unsigned int low_w = Wd[2 * ks][b2];      // keys 16ks + 4hi + 2b
        unsigned int hi_w  = Wd[2 * ks + 1][b2];  // keys 16ks + 8 + 4hi + 2b
        unsigned int msg = hi ? low_w : hi_w;     // send what the other half needs
        unsigned int rec = __shfl_xor(msg, 32);
        cvt.u[b2]     = hi ? rec : low_w;         // keys 16ks + 8hi + 2b
        cvt.u[2 + b2] = hi ? hi_w : rec;          // keys 16ks + 8hi + 4 + 2b
      }
      pf[ks] = cvt.v;
    }
    const bf16* Vp = Vbase + kgc;
    o0 = MFMA32(*(const bf16x8*)(Vp), pf[0], o0);
    o0 = MFMA32(*(const bf16x8*)(Vp + 16), pf[1], o0);
    o1 = MFMA32(*(const bf16x8*)(Vp + 32 * 2048), pf[0], o1);
    o1 = MFMA32(*(const bf16x8*)(Vp + 32 * 2048 + 16), pf[1], o1);
  };

#pragma unroll
  for (int st = 0; st < 5; ++st) {
    const bool has2 = (st < 4);
    const int c0 = st * 2, c1 = c0 + 1;
    const int kg0 = s0 + c0 * 32, kg1 = s0 + c1 * 32;
    const int kc0 = kg0 < 0 ? 0 : (kg0 > S - 32 ? S - 32 : kg0);
    const int kc1 = kg1 < 0 ? 0 : (kg1 > S - 32 ? S - 32 : kg1);

    f32x16 a0 = {}, a1 = {};
    {
      const bf16* Kp = Kbase + (size_t)(kc0 + q31) * HD;
      a0 = MFMA32(*(const bf16x8*)(Kp),      qb[0], a0);
      a0 = MFMA32(*(const bf16x8*)(Kp + 16), qb[1], a0);
      a0 = MFMA32(*(const bf16x8*)(Kp + 32), qb[2], a0);
      a0 = MFMA32(*(const bf16x8*)(Kp + 48), qb[3], a0);
    }
    if (has2) {
      const bf16* Kp = Kbase + (size_t)(kc1 + q31) * HD;
      a1 = MFMA32(*(const bf16x8*)(Kp),      qb[0], a1);
      a1 = MFMA32(*(const bf16x8*)(Kp + 16), qb[1], a1);
      a1 = MFMA32(*(const bf16x8*)(Kp + 32), qb[2], a1);
      a1 = MFMA32(*(const bf16x8*)(Kp + 48), qb[3], a1);
    }

    // masks (c0==0 / c0==8 triangles fold at compile time after unroll)
    if (kg0 != kc0) {
#pragma unroll
      for (int rg = 0; rg < 16; rg++) a0[rg] = -1e30f;
    } else if (c0 == 0) {
#pragma unroll
      for (int rg = 0; rg < 16; rg++) {
        int kk = (rg & 3) + 8 * (rg >> 2) + 4 * hi;
        if (kk < q31) a0[rg] = -1e30f;  // valid iff kk >= q
      }
    } else if (c0 == 8) {
#pragma unroll
      for (int rg = 0; rg < 16; rg++) {
        int kk = (rg & 3) + 8 * (rg >> 2) + 4 * hi;
        if (kk > q31) a0[rg] = -1e30f;  // valid iff kk <= q
      }
    }
    if (has2 && kg1 != kc1) {
#pragma unroll
      for (int rg = 0; rg < 16; rg++) a1[rg] = -1e30f;
    }

    // step max (tree) + half-wave combine
    f32x16 mx = a0;
    if (has2) {
#pragma unroll
      for (int rg = 0; rg < 16; rg++) mx[rg] = fmaxf(mx[rg], a1[rg]);
    }
#pragma unroll
    for (int sl = 8; sl >= 1; sl >>= 1)
#pragma unroll
      for (int i = 0; i < sl; i++) mx[i] = fmaxf(mx[i], mx[i + sl]);
    const float pm = fmaxf(mx[0], __shfl_xor(mx[0], 32));

    // defer-max: rescale only if max grew by > 8 (wave-uniform vote)
    if (!__all(pm - mrun <= 8.0f)) {
      const float mnew = fmaxf(mrun, pm);
      const float alpha = exp2f(mrun - mnew);
      lrun *= alpha;
#pragma unroll
      for (int rg = 0; rg < 16; rg++) { o0[rg] *= alpha; o1[rg] *= alpha; }
      mrun = mnew;
    }

    float rsum = 0.f;
#pragma unroll
    for (int rg = 0; rg < 16; rg++) { a0[rg] = exp2f(a0[rg] - mrun); rsum += a0[rg]; }
    if (has2) {
#pragma unroll
      for (int rg = 0; rg < 16; rg++) { a1[rg] = exp2f(a1[rg] - mrun); rsum += a1[rg]; }
    }
    rsum += __shfl_xor(rsum, 32);
    lrun += rsum;

    pv(a0, kc0);
    if (has2) pv(a1, kc1);
  }

  const float inv = 1.0f / lrun;
  bf16* Op = O + qrow * HD + h * DK + 4 * hi;
#pragma unroll
  for (int dt = 0; dt < 2; dt++) {
    const f32x16 oo = dt ? o1 : o0;
#pragma unroll
    for (int a = 0; a < 4; a++) {
      bf16x4 ob = {(bf16)(oo[4 * a + 0] * inv), (bf16)(oo[4 * a + 1] * inv),
                   (bf16)(oo[4 * a + 2] * inv), (bf16)(oo[4 * a + 3] * inv)};
      *(bf16x4*)(Op + dt * 32 + 8 * a) = ob;  // d = dt*32 + 8a + 4hi + (0..3)
    }
  }
}

extern "C" void kernel_launch(void* const* d_in, const int* in_sizes, int n_in,
                              void* d_out, int out_size, void* d_ws, size_t ws_size,
                              hipStream_t stream) {
  const float* hs = (const float*)d_in[0];
  const float* Wq = (const float*)d_in[1];
  const float* Wk = (const float*)d_in[2];
  const float* Wv = (const float*)d_in[3];
  const float* Wo = (const float*)d_in[4];
  float* out = (float*)d_out;

  char* ws = (char*)d_ws;
  const size_t MB = 1u << 20;
  bf16* Xb = (bf16*)(ws);                 // 16 MB, reused as attention output
  bf16* Qb = (bf16*)(ws + 16 * MB);
  bf16* Kb = (bf16*)(ws + 32 * MB);
  bf16* Vt = (bf16*)(ws + 48 * MB);       // V^T [64 bh][64 d][2048 s]
  bf16* Wtq = (bf16*)(ws + 64 * MB);
  bf16* Wtk = Wtq + 512 * 512;
  bf16* Wtv = Wtk + 512 * 512;
  bf16* Wto = Wtv + 512 * 512;
  float2* ctab = (float2*)(ws + 64 * MB + 4 * 512 * 512 * sizeof(bf16));
  bf16* AO = Xb;

  k_conv<<<dim3(Mrows * DM / (256 * 8)), dim3(256), 0, stream>>>(hs, Xb);
  k_transw4<<<dim3(16, 16, 4), dim3(32, 8), 0, stream>>>(Wq, Wk, Wv, Wo, Wtq, Wtk, Wtv, Wto);
  k_ctab<<<dim3(S * 32 / 256), dim3(256), 0, stream>>>(ctab);
  k_gemm_qkv<<<dim3(Mrows / 128, 4, 3), dim3(256), 0, stream>>>(Xb, Wtq, Wtk, Wtv, Qb, Kb, Vt, ctab);
  k_attn<<<dim3(NBLK * H * 8), dim3(256), 0, stream>>>(Qb, Kb, Vt, AO);
  k_gemm_out<<<dim3(Mrows / 128, 4), dim3(256), 0, stream>>>(AO, Wto, out);
}